// Round 11
// baseline (471.174 us; speedup 1.0000x reference)
//
#include <hip/hip_runtime.h>

constexpr int Hh = 160, Ww = 160, Bb = 8, Cc = 256, ICn = 32;
constexpr int HWn = Hh * Ww;                 // 25600
constexpr float EPSf = 1e-5f;

// ws float offsets
constexpr int P_WQH  = 0;        // ushort[96][256] qkv weight hi
constexpr int P_WQL  = 12288;    // ushort[96][256] qkv weight lo
constexpr int P_QKVB = 24576;    // [96]
constexpr int P_QKVA = 24672;    // [96]
constexpr int P_DWB  = 24768;    // ushort[3][9][32oc][32ic] dconv weights bf16
constexpr int P_DB   = 52416;    // [3][32]
constexpr int P_OWB  = 52512;    // ushort[256][96] out weight bf16
constexpr int P_OB   = 77088;    // [256]
constexpr int P_OA   = 77344;    // [1]
constexpr int PLANE  = Bb * ICn * HWn;       // 6,553,600
constexpr int OFF_Q  = 77824;
constexpr int OFF_K  = OFF_Q + PLANE;
constexpr int OFF_V  = OFF_Q + 2 * PLANE;    // Vt (dconv); then REUSED: q frag hi/lo (u16, 2*PLANE u16)
constexpr int OFF_T  = OFF_Q + 3 * PLANE;    // u16 t_frag[3][1280][5120] (bf16 MFMA A-frag image)
constexpr int OFF_TPF= OFF_T + (3 * PLANE) / 2;  // tp planar (tfrag in); then REUSED: k frag hi/lo
constexpr int OFF_CAT= OFF_Q + 6 * PLANE;    // ushort[3*PLANE] (bf16)

typedef unsigned short u16;
typedef short bf16x8 __attribute__((ext_vector_type(8)));
typedef float f32x4  __attribute__((ext_vector_type(4)));

__device__ __forceinline__ unsigned f2b(float x) {
    unsigned u = __float_as_uint(x);
    return (u + 0x7FFFu + ((u >> 16) & 1u)) >> 16;   // RNE f32->bf16
}
__device__ __forceinline__ float b2f(unsigned b) { return __uint_as_float(b << 16); }

struct InPtrs { const float* p[40]; };

// ---------------- prep: fold BN into weights/biases ----------------
__global__ void k_prep(InPtrs in, float* __restrict__ ws) {
    int idx = blockIdx.x * 256 + threadIdx.x;
    if (idx < 24576) {
        int oc = idx >> 8, c = idx & 255;
        int z = oc >> 5, o = oc & 31;
        const float* wz = in.p[1 + 6 * z];
        float s = in.p[2 + 6 * z][o] * rsqrtf(in.p[5 + 6 * z][o] + EPSf);
        float wf = wz[o * 256 + c] * s;
        unsigned hi = f2b(wf);
        unsigned lo = f2b(wf - b2f(hi));
        ((u16*)(ws + P_WQH))[oc * 256 + c] = (u16)hi;
        ((u16*)(ws + P_WQL))[oc * 256 + c] = (u16)lo;
    } else if (idx < 24672) {
        int oc = idx - 24576; int z = oc >> 5, o = oc & 31;
        float s = in.p[2 + 6 * z][o] * rsqrtf(in.p[5 + 6 * z][o] + EPSf);
        ws[P_QKVB + oc] = in.p[3 + 6 * z][o] - in.p[4 + 6 * z][o] * s;
    } else if (idx < 24768) {
        int oc = idx - 24672; int z = oc >> 5;
        ws[P_QKVA + oc] = in.p[6 + 6 * z][0];
    } else if (idx < 52416) {
        int j = idx - 24768;
        int d = j / 9216, r2 = j % 9216;
        int oc = r2 & 31; int tmp = r2 >> 5;
        int kx = tmp % 3; tmp /= 3; int ky = tmp % 3; int ic2 = tmp / 3;
        const float* wd = in.p[19 + 5 * d];
        float s = in.p[20 + 5 * d][oc] * rsqrtf(in.p[23 + 5 * d][oc] + EPSf);
        float wf = wd[((oc * 32 + ic2) * 3 + ky) * 3 + kx] * s;
        ((u16*)(ws + P_DWB))[((d * 9 + ky * 3 + kx) * 32 + oc) * 32 + ic2] = (u16)f2b(wf);
    } else if (idx < 52512) {
        int j = idx - 52416; int d = j >> 5, oc = j & 31;
        float s = in.p[20 + 5 * d][oc] * rsqrtf(in.p[23 + 5 * d][oc] + EPSf);
        ws[P_DB + j] = in.p[21 + 5 * d][oc] - in.p[22 + 5 * d][oc] * s;
    } else if (idx < 77088) {
        int j2 = idx - 52512; int c = j2 / 96;
        float s = in.p[35][c] * rsqrtf(in.p[38][c] + EPSf);
        ((u16*)(ws + P_OWB))[j2] = (u16)f2b(in.p[34][j2] * s);
    } else if (idx < 77344) {
        int c = idx - 77088;
        float s = in.p[35][c] * rsqrtf(in.p[38][c] + EPSf);
        ws[P_OB + c] = in.p[36][c] - in.p[37][c] * s;
    } else if (idx == 77344) {
        ws[P_OA] = in.p[39][0];
    }
}

// ---------------- zero Vt w-pads ----------------
__global__ __launch_bounds__(64) void k_vpad(float* __restrict__ ws) {
    u16* Vt = (u16*)(ws + OFF_V);
    size_t base = (size_t)blockIdx.x * 176 * 32;    // bh = 0..1279
    int t = threadIdx.x;
    int off = (t < 32) ? t * 8 : (168 * 32 + (t - 32) * 8);
    uint4 z = {0u, 0u, 0u, 0u};
    *(uint4*)(Vt + base + off) = z;
}

// ---------------- q/k/v 1x1 conv: MFMA GEMM M=96,K=256,N=204800 ----------------
__global__ __launch_bounds__(256) void k_qkv(const float* __restrict__ feat,
                                             float* __restrict__ ws) {
    __shared__ float FS[64 * 132];   // [64 ch][132 pad] = 33 KB
    const int tid = threadIdx.x;
    const int wv = tid >> 6, l = tid & 63;
    const int g = l >> 4, c15 = l & 15;
    const int n0 = blockIdx.x * 128;
    const int b = n0 / HWn, hw0 = n0 % HWn;
    const float* fbase = feat + (size_t)b * Cc * HWn + hw0;
    const u16* __restrict__ WQH = (const u16*)(ws + P_WQH);
    const u16* __restrict__ WQL = (const u16*)(ws + P_WQL);

    f32x4 acc[6][2];
    f32x4 z4 = {0.f, 0.f, 0.f, 0.f};
#pragma unroll
    for (int mt = 0; mt < 6; mt++) { acc[mt][0] = z4; acc[mt][1] = z4; }

    for (int kc = 0; kc < 4; kc++) {
        __syncthreads();
#pragma unroll
        for (int i = 0; i < 8; i++) {
            int f = tid + i * 256;
            int row = f >> 5, col4 = f & 31;
            float4 v = *(const float4*)(fbase + (size_t)(kc * 64 + row) * HWn + col4 * 4);
            *(float4*)(&FS[row * 132 + col4 * 4]) = v;
        }
        __syncthreads();
#pragma unroll
        for (int ks = 0; ks < 2; ks++) {
            bf16x8 bh[2], bl[2];
#pragma unroll
            for (int ntl = 0; ntl < 2; ntl++) {
                int pos = (wv * 2 + ntl) * 16 + c15;
                unsigned hw_[4], lw_[4];
#pragma unroll
                for (int v2 = 0; v2 < 4; v2++) {
                    float x0 = FS[(ks * 32 + g * 8 + 2 * v2) * 132 + pos];
                    float x1 = FS[(ks * 32 + g * 8 + 2 * v2 + 1) * 132 + pos];
                    unsigned h0 = f2b(x0), h1 = f2b(x1);
                    unsigned l0 = f2b(x0 - b2f(h0)), l1 = f2b(x1 - b2f(h1));
                    hw_[v2] = h0 | (h1 << 16);
                    lw_[v2] = l0 | (l1 << 16);
                }
                uint4 hv = {hw_[0], hw_[1], hw_[2], hw_[3]};
                uint4 lv = {lw_[0], lw_[1], lw_[2], lw_[3]};
                bh[ntl] = *(bf16x8*)&hv;
                bl[ntl] = *(bf16x8*)&lv;
            }
#pragma unroll
            for (int mt = 0; mt < 6; mt++) {
                int arow = (16 * mt + c15) * 256 + kc * 64 + ks * 32 + g * 8;
                bf16x8 ah = *(const bf16x8*)(WQH + arow);
                bf16x8 al = *(const bf16x8*)(WQL + arow);
#pragma unroll
                for (int ntl = 0; ntl < 2; ntl++) {
                    acc[mt][ntl] = __builtin_amdgcn_mfma_f32_16x16x32_bf16(ah, bh[ntl], acc[mt][ntl], 0, 0, 0);
                    acc[mt][ntl] = __builtin_amdgcn_mfma_f32_16x16x32_bf16(ah, bl[ntl], acc[mt][ntl], 0, 0, 0);
                    acc[mt][ntl] = __builtin_amdgcn_mfma_f32_16x16x32_bf16(al, bh[ntl], acc[mt][ntl], 0, 0, 0);
                }
            }
        }
    }

    // epilogue: bias + PReLU; q/k -> f32 planar, v -> bf16 Vt[b][h][w+8][ic]
    u16* vt = (u16*)(ws + OFF_V);
#pragma unroll
    for (int mt = 0; mt < 6; mt++)
#pragma unroll
        for (int ntl = 0; ntl < 2; ntl++) {
            int pos = hw0 + (wv * 2 + ntl) * 16 + c15;
            if (mt < 4) {
#pragma unroll
                for (int jr = 0; jr < 4; jr++) {
                    int oc = 16 * mt + 4 * g + jr;
                    float bb = ws[P_QKVB + oc];
                    float aa = ws[P_QKVA + oc];
                    float y = acc[mt][ntl][jr] + bb;
                    y = y >= 0.f ? y : aa * y;
                    int z = oc >> 5, o = oc & 31;
                    ws[OFF_Q + (size_t)z * PLANE + ((size_t)b * ICn + o) * HWn + pos] = y;
                }
            } else {
                int h = pos / 160, w2 = pos % 160;
                unsigned r[2];
#pragma unroll
                for (int p = 0; p < 2; p++) {
                    int oc = 16 * mt + 4 * g + 2 * p;
                    float y0 = acc[mt][ntl][2 * p]     + ws[P_QKVB + oc];
                    float y1 = acc[mt][ntl][2 * p + 1] + ws[P_QKVB + oc + 1];
                    float a0 = ws[P_QKVA + oc], a1 = ws[P_QKVA + oc + 1];
                    y0 = y0 >= 0.f ? y0 : a0 * y0;
                    y1 = y1 >= 0.f ? y1 : a1 * y1;
                    r[p] = f2b(y0) | (f2b(y1) << 16);
                }
                size_t a = ((size_t)(b * 160 + h) * 176 + w2 + 8) * 32 + (mt - 4) * 16 + 4 * g;
                uint2 dd; dd.x = r[0]; dd.y = r[1];
                *(uint2*)(vt + a) = dd;
            }
        }
}

// ---------------- dilated 3x3 convs: MFMA over ic (A=V fragments from global) ----------------
__global__ __launch_bounds__(256) void k_dconv(float* __restrict__ ws) {
    const int tid = threadIdx.x;
    const int wv = tid >> 6, l = tid & 63;
    const int g = l >> 4, c15 = l & 15;
    const int b = blockIdx.y;
    const int d = blockIdx.z;
    const int dil = 1 + 2 * d;
    const int h0 = blockIdx.x * 2;
    const u16* __restrict__ WB = (const u16*)(ws + P_DWB) + d * 9 * 32 * 32;
    bf16x8 wb[9][2];
#pragma unroll
    for (int tap = 0; tap < 9; tap++)
#pragma unroll
        for (int n = 0; n < 2; n++)
            wb[tap][n] = *(const bf16x8*)(WB + ((size_t)tap * 32 + n * 16 + c15) * 32 + g * 8);
    const u16* __restrict__ Vt = (const u16*)(ws + OFF_V) + (size_t)b * 160 * 176 * 32;
    const float bias0 = ws[P_DB + d * 32 + c15];
    const float bias1 = ws[P_DB + d * 32 + 16 + c15];
    u16* __restrict__ tp = (u16*)(ws + OFF_TPF) + (size_t)(d * Bb + b) * ICn * HWn;
    f32x4 z4 = {0.f, 0.f, 0.f, 0.f};

    for (int t5 = 0; t5 < 5; t5++) {
        int t = wv * 5 + t5;
        int h = h0 + (t >= 10);
        int w0 = (t % 10) * 16;
        f32x4 acc0 = z4, acc1 = z4;
#pragma unroll
        for (int ky = 0; ky < 3; ky++) {
            int hh = h + dil * (ky - 1);
            if ((unsigned)hh >= 160u) continue;
            const u16* row = Vt + (size_t)hh * 176 * 32;
#pragma unroll
            for (int kx = 0; kx < 3; kx++) {
                int wbase = w0 + dil * (kx - 1) + 8;
                bf16x8 av = *(const bf16x8*)(row + (size_t)(wbase + c15) * 32 + g * 8);
                acc0 = __builtin_amdgcn_mfma_f32_16x16x32_bf16(av, wb[ky * 3 + kx][0], acc0, 0, 0, 0);
                acc1 = __builtin_amdgcn_mfma_f32_16x16x32_bf16(av, wb[ky * 3 + kx][1], acc1, 0, 0, 0);
            }
        }
        size_t pixb = (size_t)h * 160 + w0 + 4 * g;
        uint2 o0, o1;
        o0.x = f2b(fmaxf(acc0[0] + bias0, 0.f)) | (f2b(fmaxf(acc0[1] + bias0, 0.f)) << 16);
        o0.y = f2b(fmaxf(acc0[2] + bias0, 0.f)) | (f2b(fmaxf(acc0[3] + bias0, 0.f)) << 16);
        o1.x = f2b(fmaxf(acc1[0] + bias1, 0.f)) | (f2b(fmaxf(acc1[1] + bias1, 0.f)) << 16);
        o1.y = f2b(fmaxf(acc1[2] + bias1, 0.f)) | (f2b(fmaxf(acc1[3] + bias1, 0.f)) << 16);
        *(uint2*)(tp + (size_t)c15 * HWn + pixb) = o0;
        *(uint2*)(tp + (size_t)(16 + c15) * HWn + pixb) = o1;
    }
}

// ---------------- t re-layout: planar bf16 -> MFMA A-frag image ----------------
__global__ __launch_bounds__(256) void k_tfrag(float* __restrict__ ws) {
    __shared__ u16 fr[4][5120];
    const int tid = threadIdx.x;
    const int wq = blockIdx.x;      // 0..39
    const int b  = blockIdx.y;      // 0..7
    const int d  = blockIdx.z;      // 0..2
    const int w0 = wq * 4;
    const u16* __restrict__ tp = (const u16*)(ws + OFF_TPF) + (size_t)(d * Bb + b) * ICn * HWn;
    for (int i = tid; i < 5120; i += 256) {
        int ic = i / 160, h = i % 160;
        uint2 v = *(const uint2*)(tp + (size_t)ic * HWn + h * Ww + w0);
        fr[0][i] = (u16)(v.x & 0xFFFFu);
        fr[1][i] = (u16)(v.x >> 16);
        fr[2][i] = (u16)(v.y & 0xFFFFu);
        fr[3][i] = (u16)(v.y >> 16);
    }
    __syncthreads();
    u16* __restrict__ tf = (u16*)(ws + OFF_T);
#pragma unroll
    for (int it = 0; it < 10; it++) {
        int W = tid + it * 256;          // 0..2559
        int s = W / 640, word = W % 640;
        int slot = word >> 6, lane = word & 63;
        int jc = (lane & 15) | ((slot / 5) << 4);
        int h2b = ((slot % 5) << 5) | (((lane >> 4) & 3) << 3);
        unsigned r[4];
#pragma unroll
        for (int p = 0; p < 4; p++) {
            int f0 = (h2b + 2 * p) * 32 + jc;
            unsigned lo = fr[s][f0];
            unsigned hi = fr[s][f0 + 32];
            r[p] = lo | (hi << 16);
        }
        uint4 o4 = {r[0], r[1], r[2], r[3]};
        *(uint4*)(tf + ((size_t)d * 1280 + b * 160 + w0 + s) * 5120 + word * 8) = o4;
    }
}

// ---------------- q/k re-layout: planar f32 -> hi/lo bf16 MFMA frag images ----------------
// z=0: q plane -> OFF_V region (Vt dead after k_dconv). z=1: k plane -> OFF_TPF region (tp dead after k_tfrag).
__global__ __launch_bounds__(256) void k_qkfrag(float* __restrict__ ws) {
    extern __shared__ float frf[];   // [4][5120] f32 = 80 KB
    const int tid = threadIdx.x;
    const int wq = blockIdx.x;      // 0..39
    const int b  = blockIdx.y;      // 0..7
    const int z  = blockIdx.z;      // 0=q, 1=k
    const int w0 = wq * 4;
    const float* __restrict__ in = ws + (z ? OFF_K : OFF_Q) + (size_t)b * ICn * HWn;
    u16* __restrict__ outb = (u16*)(ws + (z ? OFF_TPF : OFF_V));

    for (int i = tid; i < 5120; i += 256) {
        int ic = i / 160, h = i % 160;
        float4 v = *(const float4*)(in + (size_t)ic * HWn + h * 160 + w0);
        frf[0 * 5120 + i] = v.x;
        frf[1 * 5120 + i] = v.y;
        frf[2 * 5120 + i] = v.z;
        frf[3 * 5120 + i] = v.w;
    }
    __syncthreads();
#pragma unroll
    for (int it = 0; it < 10; it++) {
        int W = tid + it * 256;          // 0..2559
        int s = W / 640, word = W % 640;
        int lane = word & 63, tau = word >> 6;
        int h = tau * 16 + (lane & 15);
        int icb = (lane >> 4) * 8;
        unsigned hw_[4], lw_[4];
#pragma unroll
        for (int p = 0; p < 4; p++) {
            float x0 = frf[s * 5120 + (icb + 2 * p) * 160 + h];
            float x1 = frf[s * 5120 + (icb + 2 * p + 1) * 160 + h];
            unsigned h0 = f2b(x0), h1 = f2b(x1);
            unsigned l0 = f2b(x0 - b2f(h0)), l1 = f2b(x1 - b2f(h1));
            hw_[p] = h0 | (h1 << 16);
            lw_[p] = l0 | (l1 << 16);
        }
        uint4 hv = {hw_[0], hw_[1], hw_[2], hw_[3]};
        uint4 lv = {lw_[0], lw_[1], lw_[2], lw_[3]};
        size_t o = (size_t)(b * 160 + w0 + s) * 5120 + word * 8;
        *(uint4*)(outb + o) = hv;
        *(uint4*)(outb + (size_t)PLANE + o) = lv;    // lo plane offset = PLANE u16s
    }
}

// ---------------- attention: MFMA bf16; q/k/t all read as frag images from global ----------------
__global__ __launch_bounds__(320) void k_att(float* __restrict__ ws) {
    __shared__ char Sb[51200];       // wave-private S slots: 50 x 64 lanes x 16B
    const int tid = threadIdx.x;
    const int bid = blockIdx.x;
    const int r8 = bid & 7, qq = bid >> 3;   // XCD swizzle
    const int b = qq / 20;
    const int w = r8 * 20 + (qq % 20);
    const int bw = b * Ww + w;
    const int wv = tid >> 6;
    const int l  = tid & 63;
    const int g  = l >> 4;
    const int c  = l & 15;
    const int slice = b * 160 + w;

    const u16* __restrict__ qh = (const u16*)(ws + OFF_V)   + (size_t)slice * 5120;
    const u16* __restrict__ ql = qh + (size_t)PLANE;
    const u16* __restrict__ kh = (const u16*)(ws + OFF_TPF) + (size_t)slice * 5120;
    const u16* __restrict__ kl = kh + (size_t)PLANE;

    bf16x8 bq[2][2];
#pragma unroll
    for (int ct = 0; ct < 2; ct++) {
        int tau = 2 * wv + ct;
        bq[ct][0] = *(const bf16x8*)(qh + (tau * 64 + l) * 8);
        bq[ct][1] = *(const bf16x8*)(ql + (tau * 64 + l) * 8);
    }
    f32x4 acc[10][2];
    f32x4 z4 = {0.f, 0.f, 0.f, 0.f};
#pragma unroll
    for (int rt = 0; rt < 10; rt++) { acc[rt][0] = z4; acc[rt][1] = z4; }
#pragma unroll
    for (int rt = 0; rt < 10; rt++) {
        bf16x8 ah = *(const bf16x8*)(kh + (rt * 64 + l) * 8);
        bf16x8 al = *(const bf16x8*)(kl + (rt * 64 + l) * 8);
#pragma unroll
        for (int ct = 0; ct < 2; ct++) {
            acc[rt][ct] = __builtin_amdgcn_mfma_f32_16x16x32_bf16(ah, bq[ct][0], acc[rt][ct], 0, 0, 0);
            acc[rt][ct] = __builtin_amdgcn_mfma_f32_16x16x32_bf16(ah, bq[ct][1], acc[rt][ct], 0, 0, 0);
            acc[rt][ct] = __builtin_amdgcn_mfma_f32_16x16x32_bf16(al, bq[ct][0], acc[rt][ct], 0, 0, 0);
        }
    }

    float mx[2] = {-3.4e38f, -3.4e38f};
#pragma unroll
    for (int rt = 0; rt < 10; rt++)
#pragma unroll
        for (int ct = 0; ct < 2; ct++)
#pragma unroll
            for (int j = 0; j < 4; j++) mx[ct] = fmaxf(mx[ct], acc[rt][ct][j]);
#pragma unroll
    for (int ct = 0; ct < 2; ct++) {
        mx[ct] = fmaxf(mx[ct], __shfl_xor(mx[ct], 16));
        mx[ct] = fmaxf(mx[ct], __shfl_xor(mx[ct], 32));
    }
    float sm[2] = {0.f, 0.f};
#pragma unroll
    for (int rt = 0; rt < 10; rt++)
#pragma unroll
        for (int ct = 0; ct < 2; ct++)
#pragma unroll
            for (int j = 0; j < 4; j++) {
                float e = __expf(acc[rt][ct][j] - mx[ct]);
                acc[rt][ct][j] = e;
                sm[ct] += e;
            }
#pragma unroll
    for (int ct = 0; ct < 2; ct++) {
        sm[ct] += __shfl_xor(sm[ct], 16);
        sm[ct] += __shfl_xor(sm[ct], 32);
    }
    float inv[2] = {1.f / sm[0], 1.f / sm[1]};

    // S repack: wave-private slots -> no barriers needed (lgkmcnt orders within wave)
#pragma unroll
    for (int rt = 0; rt < 10; rt++) {
#pragma unroll
        for (int ct = 0; ct < 2; ct++) {
            float p0 = acc[rt][ct][0] * inv[ct];
            float p1 = acc[rt][ct][1] * inv[ct];
            float p2 = acc[rt][ct][2] * inv[ct];
            float p3 = acc[rt][ct][3] * inv[ct];
            unsigned d0 = f2b(p0) | (f2b(p1) << 16);
            unsigned d1 = f2b(p2) | (f2b(p3) << 16);
            int Lf = c + 16 * (2 * (rt & 1) + (g >> 1));
            char* dst = Sb + (((wv * 2 + ct) * 5 + (rt >> 1)) * 64 + Lf) * 16 + 8 * (g & 1);
            uint2 dd; dd.x = d0; dd.y = d1;
            *(uint2*)dst = dd;
        }
    }

    const u16* tf = (const u16*)(ws + OFF_T);
    u16* catb = (u16*)(ws + OFF_CAT);
    for (int d = 0; d < 3; d++) {
        const u16* tfd = tf + ((size_t)d * (Bb * Ww) + bw) * 5120;
        f32x4 po[2][2];
        po[0][0] = z4; po[0][1] = z4; po[1][0] = z4; po[1][1] = z4;
#pragma unroll
        for (int ks = 0; ks < 5; ks++) {
            bf16x8 a0 = *(const bf16x8*)(tfd + ((0 * 5 + ks) * 64 + l) * 8);   // coalesced 16B/lane
            bf16x8 a1 = *(const bf16x8*)(tfd + ((1 * 5 + ks) * 64 + l) * 8);
            bf16x8 s0 = *(bf16x8*)(Sb + (((wv * 2 + 0) * 5 + ks) * 64 + l) * 16);
            bf16x8 s1 = *(bf16x8*)(Sb + (((wv * 2 + 1) * 5 + ks) * 64 + l) * 16);
            po[0][0] = __builtin_amdgcn_mfma_f32_16x16x32_bf16(a0, s0, po[0][0], 0, 0, 0);
            po[0][1] = __builtin_amdgcn_mfma_f32_16x16x32_bf16(a0, s1, po[0][1], 0, 0, 0);
            po[1][0] = __builtin_amdgcn_mfma_f32_16x16x32_bf16(a1, s0, po[1][0], 0, 0, 0);
            po[1][1] = __builtin_amdgcn_mfma_f32_16x16x32_bf16(a1, s1, po[1][1], 0, 0, 0);
        }
#pragma unroll
        for (int jt = 0; jt < 2; jt++)
#pragma unroll
            for (int ct = 0; ct < 2; ct++) {
                int h1 = 32 * wv + 16 * ct + c;
                size_t idx = (size_t)d * PLANE + (size_t)bw * 5120 + h1 * 32 + 16 * jt + 4 * g;
                f32x4 v = po[jt][ct];
                uint2 dd;
                dd.x = f2b(v[0]) | (f2b(v[1]) << 16);
                dd.y = f2b(v[2]) | (f2b(v[3]) << 16);
                *(uint2*)(catb + idx) = dd;
            }
    }
}

// ---------------- output 1x1 conv: bf16 MFMA GEMM M=256,K=96,N=204800 ----------------
__global__ __launch_bounds__(256) void k_out(const float* __restrict__ feat,
                                             const float* __restrict__ ws,
                                             float* __restrict__ out) {
    __shared__ u16 Bs[12288];   // 24 slots(ks,nt) x 64 lanes x 8 bf16
    const int tid = threadIdx.x;
    const int wv = tid >> 6, l = tid & 63;
    const int g = l >> 4, c15 = l & 15;
    const int n0 = blockIdx.x * 128;
    const int b = n0 / HWn, hw0 = n0 % HWn;
    const u16* __restrict__ CATb = (const u16*)(ws + OFF_CAT);
    const u16* __restrict__ OWB = (const u16*)(ws + P_OWB);

#pragma unroll
    for (int ss = 0; ss < 6; ss++) {
        int s = tid + ss * 256;
        int sl = s & 63, si = s >> 6;    // si = ks*8+nt, 0..23
        int p = (si & 7) * 16 + (sl & 15);
        int hw = hw0 + p;
        int h = hw / Ww, w2 = hw % Ww;
        int j = (si >> 3) * 32 + (sl >> 4) * 8;
        size_t flat = ((size_t)(b * Ww + w2) * Hh + h) * 96 + j;
        *(uint4*)(&Bs[(si * 64 + sl) * 8]) = *(const uint4*)(CATb + flat);
    }
    bf16x8 af[4][3];
#pragma unroll
    for (int mt = 0; mt < 4; mt++)
#pragma unroll
        for (int ks = 0; ks < 3; ks++)
            af[mt][ks] = *(const bf16x8*)(OWB + (wv * 64 + mt * 16 + c15) * 96 + ks * 32 + g * 8);
    __syncthreads();
    const float alpha = ws[P_OA];

    f32x4 z4 = {0.f, 0.f, 0.f, 0.f};
#pragma unroll
    for (int np = 0; np < 2; np++) {
        f32x4 acc[4][4];
#pragma unroll
        for (int mt = 0; mt < 4; mt++)
#pragma unroll
            for (int ntl = 0; ntl < 4; ntl++) acc[mt][ntl] = z4;
#pragma unroll
        for (int ks = 0; ks < 3; ks++) {
            bf16x8 bf_[4];
#pragma unroll
            for (int ntl = 0; ntl < 4; ntl++)
                bf_[ntl] = *(const bf16x8*)(&Bs[((ks * 8 + np * 4 + ntl) * 64 + l) * 8]);
#pragma unroll
            for (int mt = 0; mt < 4; mt++)
#pragma unroll
                for (int ntl = 0; ntl < 4; ntl++)
                    acc[mt][ntl] = __builtin_amdgcn_mfma_f32_16x16x32_bf16(af[mt][ks], bf_[ntl], acc[mt][ntl], 0, 0, 0);
        }
#pragma unroll
        for (int mt = 0; mt < 4; mt++)
#pragma unroll
            for (int ntl = 0; ntl < 4; ntl++) {
                int p = (np * 4 + ntl) * 16 + c15;
#pragma unroll
                for (int jr = 0; jr < 4; jr++) {
                    int cch = wv * 64 + mt * 16 + 4 * g + jr;
                    size_t base = ((size_t)b * Cc + cch) * HWn + hw0 + p;
                    float y = acc[mt][ntl][jr] + ws[P_OB + cch] + feat[base];
                    out[base] = y >= 0.f ? y : alpha * y;
                }
            }
    }
}

extern "C" void kernel_launch(void* const* d_in, const int* in_sizes, int n_in,
                              void* d_out, int out_size, void* d_ws, size_t ws_size,
                              hipStream_t stream) {
    InPtrs ip;
    for (int i = 0; i < 40; i++) ip.p[i] = (const float*)d_in[i];
    float* ws = (float*)d_ws;
    const float* feat = (const float*)d_in[0];
    float* out = (float*)d_out;

    k_prep<<<304, 256, 0, stream>>>(ip, ws);
    k_vpad<<<1280, 64, 0, stream>>>(ws);
    k_qkv<<<1600, 256, 0, stream>>>(feat, ws);
    k_dconv<<<dim3(80, 8, 3), 256, 0, stream>>>(ws);
    k_tfrag<<<dim3(40, 8, 3), 256, 0, stream>>>(ws);
    (void)hipFuncSetAttribute(reinterpret_cast<const void*>(k_qkfrag),
                              hipFuncAttributeMaxDynamicSharedMemorySize, 81920);
    k_qkfrag<<<dim3(40, 8, 2), 256, 81920, stream>>>(ws);
    k_att<<<1280, 320, 0, stream>>>(ws);
    k_out<<<1600, 256, 0, stream>>>(feat, ws, out);
}

// Round 12
// 441.288 us; speedup vs baseline: 1.0677x; 1.0677x over previous
//
#include <hip/hip_runtime.h>

constexpr int Hh = 160, Ww = 160, Bb = 8, Cc = 256, ICn = 32;
constexpr int HWn = Hh * Ww;                 // 25600
constexpr float EPSf = 1e-5f;

// ws float offsets
constexpr int P_WQH  = 0;        // ushort[96][256] qkv weight hi
constexpr int P_WQL  = 12288;    // ushort[96][256] qkv weight lo
constexpr int P_QKVB = 24576;    // [96]
constexpr int P_QKVA = 24672;    // [96]
constexpr int P_DWB  = 24768;    // ushort[3][9][32oc][32ic] dconv weights bf16
constexpr int P_DB   = 52416;    // [3][32]
constexpr int P_OWB  = 52512;    // ushort[256][96] out weight bf16
constexpr int P_OB   = 77088;    // [256]
constexpr int P_OA   = 77344;    // [1]
constexpr int PLANE  = Bb * ICn * HWn;       // 6,553,600
constexpr int OFF_Q  = 77824;
constexpr int OFF_K  = OFF_Q + PLANE;
constexpr int OFF_V  = OFF_Q + 2 * PLANE;    // Vt (dconv); then REUSED: q frag hi/lo (u16, 2*PLANE u16)
constexpr int OFF_T  = OFF_Q + 3 * PLANE;    // u16 t_frag[3][1280][5120] (bf16 MFMA A-frag image)
constexpr int OFF_TPF= OFF_T + (3 * PLANE) / 2;  // tp planar (tfrag in); then REUSED: k frag hi/lo
constexpr int OFF_CAT= OFF_Q + 6 * PLANE;    // ushort[3*PLANE] (bf16)

typedef unsigned short u16;
typedef short bf16x8 __attribute__((ext_vector_type(8)));
typedef float f32x4  __attribute__((ext_vector_type(4)));

__device__ __forceinline__ unsigned f2b(float x) {
    unsigned u = __float_as_uint(x);
    return (u + 0x7FFFu + ((u >> 16) & 1u)) >> 16;   // RNE f32->bf16
}
__device__ __forceinline__ float b2f(unsigned b) { return __uint_as_float(b << 16); }

struct InPtrs { const float* p[40]; };

// ---------------- prep: fold BN into weights/biases ----------------
__global__ void k_prep(InPtrs in, float* __restrict__ ws) {
    int idx = blockIdx.x * 256 + threadIdx.x;
    if (idx < 24576) {
        int oc = idx >> 8, c = idx & 255;
        int z = oc >> 5, o = oc & 31;
        const float* wz = in.p[1 + 6 * z];
        float s = in.p[2 + 6 * z][o] * rsqrtf(in.p[5 + 6 * z][o] + EPSf);
        float wf = wz[o * 256 + c] * s;
        unsigned hi = f2b(wf);
        unsigned lo = f2b(wf - b2f(hi));
        ((u16*)(ws + P_WQH))[oc * 256 + c] = (u16)hi;
        ((u16*)(ws + P_WQL))[oc * 256 + c] = (u16)lo;
    } else if (idx < 24672) {
        int oc = idx - 24576; int z = oc >> 5, o = oc & 31;
        float s = in.p[2 + 6 * z][o] * rsqrtf(in.p[5 + 6 * z][o] + EPSf);
        ws[P_QKVB + oc] = in.p[3 + 6 * z][o] - in.p[4 + 6 * z][o] * s;
    } else if (idx < 24768) {
        int oc = idx - 24672; int z = oc >> 5;
        ws[P_QKVA + oc] = in.p[6 + 6 * z][0];
    } else if (idx < 52416) {
        int j = idx - 24768;
        int d = j / 9216, r2 = j % 9216;
        int oc = r2 & 31; int tmp = r2 >> 5;
        int kx = tmp % 3; tmp /= 3; int ky = tmp % 3; int ic2 = tmp / 3;
        const float* wd = in.p[19 + 5 * d];
        float s = in.p[20 + 5 * d][oc] * rsqrtf(in.p[23 + 5 * d][oc] + EPSf);
        float wf = wd[((oc * 32 + ic2) * 3 + ky) * 3 + kx] * s;
        ((u16*)(ws + P_DWB))[((d * 9 + ky * 3 + kx) * 32 + oc) * 32 + ic2] = (u16)f2b(wf);
    } else if (idx < 52512) {
        int j = idx - 52416; int d = j >> 5, oc = j & 31;
        float s = in.p[20 + 5 * d][oc] * rsqrtf(in.p[23 + 5 * d][oc] + EPSf);
        ws[P_DB + j] = in.p[21 + 5 * d][oc] - in.p[22 + 5 * d][oc] * s;
    } else if (idx < 77088) {
        int j2 = idx - 52512; int c = j2 / 96;
        float s = in.p[35][c] * rsqrtf(in.p[38][c] + EPSf);
        ((u16*)(ws + P_OWB))[j2] = (u16)f2b(in.p[34][j2] * s);
    } else if (idx < 77344) {
        int c = idx - 77088;
        float s = in.p[35][c] * rsqrtf(in.p[38][c] + EPSf);
        ws[P_OB + c] = in.p[36][c] - in.p[37][c] * s;
    } else if (idx == 77344) {
        ws[P_OA] = in.p[39][0];
    }
}

// ---------------- zero Vt w-pads ----------------
__global__ __launch_bounds__(64) void k_vpad(float* __restrict__ ws) {
    u16* Vt = (u16*)(ws + OFF_V);
    size_t base = (size_t)blockIdx.x * 176 * 32;    // bh = 0..1279
    int t = threadIdx.x;
    int off = (t < 32) ? t * 8 : (168 * 32 + (t - 32) * 8);
    uint4 z = {0u, 0u, 0u, 0u};
    *(uint4*)(Vt + base + off) = z;
}

// ---------------- q/k/v 1x1 conv: MFMA GEMM M=96,K=256,N=204800 ----------------
// grid 1600, block 256 = 4 waves; N-tile 128; K-chunk 32, double-buffered LDS with
// reg-staged prefetch (T14): global loads -> regs fly under compute; barriers carry
// no vmcnt drain.
__global__ __launch_bounds__(256, 4) void k_qkv(const float* __restrict__ feat,
                                                float* __restrict__ ws) {
    __shared__ float FS[2][32 * 132];   // 2 x 16.9 KB = 33.8 KB
    const int tid = threadIdx.x;
    const int wv = tid >> 6, l = tid & 63;
    const int g = l >> 4, c15 = l & 15;
    const int n0 = blockIdx.x * 128;
    const int b = n0 / HWn, hw0 = n0 % HWn;
    const float* fbase = feat + (size_t)b * Cc * HWn + hw0;
    const u16* __restrict__ WQH = (const u16*)(ws + P_WQH);
    const u16* __restrict__ WQL = (const u16*)(ws + P_WQL);

    f32x4 acc[6][2];
    f32x4 z4 = {0.f, 0.f, 0.f, 0.f};
#pragma unroll
    for (int mt = 0; mt < 6; mt++) { acc[mt][0] = z4; acc[mt][1] = z4; }

    float4 pre0, pre1, pre2, pre3;
    // prologue: chunk 0 -> regs -> FS[0]
    {
        int f0 = tid, f1 = tid + 256, f2 = tid + 512, f3 = tid + 768;
        pre0 = *(const float4*)(fbase + (size_t)(f0 >> 5) * HWn + (f0 & 31) * 4);
        pre1 = *(const float4*)(fbase + (size_t)(f1 >> 5) * HWn + (f1 & 31) * 4);
        pre2 = *(const float4*)(fbase + (size_t)(f2 >> 5) * HWn + (f2 & 31) * 4);
        pre3 = *(const float4*)(fbase + (size_t)(f3 >> 5) * HWn + (f3 & 31) * 4);
        *(float4*)(&FS[0][(f0 >> 5) * 132 + (f0 & 31) * 4]) = pre0;
        *(float4*)(&FS[0][(f1 >> 5) * 132 + (f1 & 31) * 4]) = pre1;
        *(float4*)(&FS[0][(f2 >> 5) * 132 + (f2 & 31) * 4]) = pre2;
        *(float4*)(&FS[0][(f3 >> 5) * 132 + (f3 & 31) * 4]) = pre3;
    }
    __syncthreads();

    for (int kc = 0; kc < 8; kc++) {
        const int cur = kc & 1;
        // prefetch next chunk into regs (flies under compute below)
        if (kc < 7) {
            int base = (kc + 1) * 32;
            int f0 = tid, f1 = tid + 256, f2 = tid + 512, f3 = tid + 768;
            pre0 = *(const float4*)(fbase + (size_t)(base + (f0 >> 5)) * HWn + (f0 & 31) * 4);
            pre1 = *(const float4*)(fbase + (size_t)(base + (f1 >> 5)) * HWn + (f1 & 31) * 4);
            pre2 = *(const float4*)(fbase + (size_t)(base + (f2 >> 5)) * HWn + (f2 & 31) * 4);
            pre3 = *(const float4*)(fbase + (size_t)(base + (f3 >> 5)) * HWn + (f3 & 31) * 4);
        }
        // compute chunk kc from FS[cur]
        bf16x8 bh[2], bl[2];
#pragma unroll
        for (int ntl = 0; ntl < 2; ntl++) {
            int pos = (wv * 2 + ntl) * 16 + c15;
            unsigned hw_[4], lw_[4];
#pragma unroll
            for (int v2 = 0; v2 < 4; v2++) {
                float x0 = FS[cur][(g * 8 + 2 * v2) * 132 + pos];
                float x1 = FS[cur][(g * 8 + 2 * v2 + 1) * 132 + pos];
                unsigned h0 = f2b(x0), h1 = f2b(x1);
                unsigned l0 = f2b(x0 - b2f(h0)), l1 = f2b(x1 - b2f(h1));
                hw_[v2] = h0 | (h1 << 16);
                lw_[v2] = l0 | (l1 << 16);
            }
            uint4 hv = {hw_[0], hw_[1], hw_[2], hw_[3]};
            uint4 lv = {lw_[0], lw_[1], lw_[2], lw_[3]};
            bh[ntl] = *(bf16x8*)&hv;
            bl[ntl] = *(bf16x8*)&lv;
        }
#pragma unroll
        for (int mt = 0; mt < 6; mt++) {
            int arow = (16 * mt + c15) * 256 + kc * 32 + g * 8;
            bf16x8 ah = *(const bf16x8*)(WQH + arow);
            bf16x8 al = *(const bf16x8*)(WQL + arow);
#pragma unroll
            for (int ntl = 0; ntl < 2; ntl++) {
                acc[mt][ntl] = __builtin_amdgcn_mfma_f32_16x16x32_bf16(ah, bh[ntl], acc[mt][ntl], 0, 0, 0);
                acc[mt][ntl] = __builtin_amdgcn_mfma_f32_16x16x32_bf16(ah, bl[ntl], acc[mt][ntl], 0, 0, 0);
                acc[mt][ntl] = __builtin_amdgcn_mfma_f32_16x16x32_bf16(al, bh[ntl], acc[mt][ntl], 0, 0, 0);
            }
        }
        if (kc < 7) {
            __syncthreads();   // all waves done reading FS[cur^1] (two chunks ago)
            int f0 = tid, f1 = tid + 256, f2 = tid + 512, f3 = tid + 768;
            float* nb = FS[cur ^ 1];
            *(float4*)(&nb[(f0 >> 5) * 132 + (f0 & 31) * 4]) = pre0;
            *(float4*)(&nb[(f1 >> 5) * 132 + (f1 & 31) * 4]) = pre1;
            *(float4*)(&nb[(f2 >> 5) * 132 + (f2 & 31) * 4]) = pre2;
            *(float4*)(&nb[(f3 >> 5) * 132 + (f3 & 31) * 4]) = pre3;
            __syncthreads();   // next chunk visible to all
        }
    }

    // epilogue: bias + PReLU; q/k -> f32 planar, v -> bf16 Vt[b][h][w+8][ic]
    u16* vt = (u16*)(ws + OFF_V);
#pragma unroll
    for (int mt = 0; mt < 6; mt++)
#pragma unroll
        for (int ntl = 0; ntl < 2; ntl++) {
            int pos = hw0 + (wv * 2 + ntl) * 16 + c15;
            if (mt < 4) {
#pragma unroll
                for (int jr = 0; jr < 4; jr++) {
                    int oc = 16 * mt + 4 * g + jr;
                    float bb = ws[P_QKVB + oc];
                    float aa = ws[P_QKVA + oc];
                    float y = acc[mt][ntl][jr] + bb;
                    y = y >= 0.f ? y : aa * y;
                    int z = oc >> 5, o = oc & 31;
                    ws[OFF_Q + (size_t)z * PLANE + ((size_t)b * ICn + o) * HWn + pos] = y;
                }
            } else {
                int h = pos / 160, w2 = pos % 160;
                unsigned r[2];
#pragma unroll
                for (int p = 0; p < 2; p++) {
                    int oc = 16 * mt + 4 * g + 2 * p;
                    float y0 = acc[mt][ntl][2 * p]     + ws[P_QKVB + oc];
                    float y1 = acc[mt][ntl][2 * p + 1] + ws[P_QKVB + oc + 1];
                    float a0 = ws[P_QKVA + oc], a1 = ws[P_QKVA + oc + 1];
                    y0 = y0 >= 0.f ? y0 : a0 * y0;
                    y1 = y1 >= 0.f ? y1 : a1 * y1;
                    r[p] = f2b(y0) | (f2b(y1) << 16);
                }
                size_t a = ((size_t)(b * 160 + h) * 176 + w2 + 8) * 32 + (mt - 4) * 16 + 4 * g;
                uint2 dd; dd.x = r[0]; dd.y = r[1];
                *(uint2*)(vt + a) = dd;
            }
        }
}

// ---------------- dilated 3x3 convs: MFMA over ic (A=V fragments from global) ----------------
__global__ __launch_bounds__(256) void k_dconv(float* __restrict__ ws) {
    const int tid = threadIdx.x;
    const int wv = tid >> 6, l = tid & 63;
    const int g = l >> 4, c15 = l & 15;
    const int b = blockIdx.y;
    const int d = blockIdx.z;
    const int dil = 1 + 2 * d;
    const int h0 = blockIdx.x * 2;
    const u16* __restrict__ WB = (const u16*)(ws + P_DWB) + d * 9 * 32 * 32;
    bf16x8 wb[9][2];
#pragma unroll
    for (int tap = 0; tap < 9; tap++)
#pragma unroll
        for (int n = 0; n < 2; n++)
            wb[tap][n] = *(const bf16x8*)(WB + ((size_t)tap * 32 + n * 16 + c15) * 32 + g * 8);
    const u16* __restrict__ Vt = (const u16*)(ws + OFF_V) + (size_t)b * 160 * 176 * 32;
    const float bias0 = ws[P_DB + d * 32 + c15];
    const float bias1 = ws[P_DB + d * 32 + 16 + c15];
    u16* __restrict__ tp = (u16*)(ws + OFF_TPF) + (size_t)(d * Bb + b) * ICn * HWn;
    f32x4 z4 = {0.f, 0.f, 0.f, 0.f};

    for (int t5 = 0; t5 < 5; t5++) {
        int t = wv * 5 + t5;
        int h = h0 + (t >= 10);
        int w0 = (t % 10) * 16;
        f32x4 acc0 = z4, acc1 = z4;
#pragma unroll
        for (int ky = 0; ky < 3; ky++) {
            int hh = h + dil * (ky - 1);
            if ((unsigned)hh >= 160u) continue;
            const u16* row = Vt + (size_t)hh * 176 * 32;
#pragma unroll
            for (int kx = 0; kx < 3; kx++) {
                int wbase = w0 + dil * (kx - 1) + 8;
                bf16x8 av = *(const bf16x8*)(row + (size_t)(wbase + c15) * 32 + g * 8);
                acc0 = __builtin_amdgcn_mfma_f32_16x16x32_bf16(av, wb[ky * 3 + kx][0], acc0, 0, 0, 0);
                acc1 = __builtin_amdgcn_mfma_f32_16x16x32_bf16(av, wb[ky * 3 + kx][1], acc1, 0, 0, 0);
            }
        }
        size_t pixb = (size_t)h * 160 + w0 + 4 * g;
        uint2 o0, o1;
        o0.x = f2b(fmaxf(acc0[0] + bias0, 0.f)) | (f2b(fmaxf(acc0[1] + bias0, 0.f)) << 16);
        o0.y = f2b(fmaxf(acc0[2] + bias0, 0.f)) | (f2b(fmaxf(acc0[3] + bias0, 0.f)) << 16);
        o1.x = f2b(fmaxf(acc1[0] + bias1, 0.f)) | (f2b(fmaxf(acc1[1] + bias1, 0.f)) << 16);
        o1.y = f2b(fmaxf(acc1[2] + bias1, 0.f)) | (f2b(fmaxf(acc1[3] + bias1, 0.f)) << 16);
        *(uint2*)(tp + (size_t)c15 * HWn + pixb) = o0;
        *(uint2*)(tp + (size_t)(16 + c15) * HWn + pixb) = o1;
    }
}

// ---------------- t re-layout: planar bf16 -> MFMA A-frag image ----------------
__global__ __launch_bounds__(256) void k_tfrag(float* __restrict__ ws) {
    __shared__ u16 fr[4][5120];
    const int tid = threadIdx.x;
    const int wq = blockIdx.x;      // 0..39
    const int b  = blockIdx.y;      // 0..7
    const int d  = blockIdx.z;      // 0..2
    const int w0 = wq * 4;
    const u16* __restrict__ tp = (const u16*)(ws + OFF_TPF) + (size_t)(d * Bb + b) * ICn * HWn;
    for (int i = tid; i < 5120; i += 256) {
        int ic = i / 160, h = i % 160;
        uint2 v = *(const uint2*)(tp + (size_t)ic * HWn + h * Ww + w0);
        fr[0][i] = (u16)(v.x & 0xFFFFu);
        fr[1][i] = (u16)(v.x >> 16);
        fr[2][i] = (u16)(v.y & 0xFFFFu);
        fr[3][i] = (u16)(v.y >> 16);
    }
    __syncthreads();
    u16* __restrict__ tf = (u16*)(ws + OFF_T);
#pragma unroll
    for (int it = 0; it < 10; it++) {
        int W = tid + it * 256;          // 0..2559
        int s = W / 640, word = W % 640;
        int slot = word >> 6, lane = word & 63;
        int jc = (lane & 15) | ((slot / 5) << 4);
        int h2b = ((slot % 5) << 5) | (((lane >> 4) & 3) << 3);
        unsigned r[4];
#pragma unroll
        for (int p = 0; p < 4; p++) {
            int f0 = (h2b + 2 * p) * 32 + jc;
            unsigned lo = fr[s][f0];
            unsigned hi = fr[s][f0 + 32];
            r[p] = lo | (hi << 16);
        }
        uint4 o4 = {r[0], r[1], r[2], r[3]};
        *(uint4*)(tf + ((size_t)d * 1280 + b * 160 + w0 + s) * 5120 + word * 8) = o4;
    }
}

// ---------------- q/k re-layout: planar f32 -> hi/lo bf16 MFMA frag images ----------------
__global__ __launch_bounds__(256) void k_qkfrag(float* __restrict__ ws) {
    extern __shared__ float frf[];   // [4][5120] f32 = 80 KB
    const int tid = threadIdx.x;
    const int wq = blockIdx.x;      // 0..39
    const int b  = blockIdx.y;      // 0..7
    const int z  = blockIdx.z;      // 0=q, 1=k
    const int w0 = wq * 4;
    const float* __restrict__ in = ws + (z ? OFF_K : OFF_Q) + (size_t)b * ICn * HWn;
    u16* __restrict__ outb = (u16*)(ws + (z ? OFF_TPF : OFF_V));

    for (int i = tid; i < 5120; i += 256) {
        int ic = i / 160, h = i % 160;
        float4 v = *(const float4*)(in + (size_t)ic * HWn + h * 160 + w0);
        frf[0 * 5120 + i] = v.x;
        frf[1 * 5120 + i] = v.y;
        frf[2 * 5120 + i] = v.z;
        frf[3 * 5120 + i] = v.w;
    }
    __syncthreads();
#pragma unroll
    for (int it = 0; it < 10; it++) {
        int W = tid + it * 256;          // 0..2559
        int s = W / 640, word = W % 640;
        int lane = word & 63, tau = word >> 6;
        int h = tau * 16 + (lane & 15);
        int icb = (lane >> 4) * 8;
        unsigned hw_[4], lw_[4];
#pragma unroll
        for (int p = 0; p < 4; p++) {
            float x0 = frf[s * 5120 + (icb + 2 * p) * 160 + h];
            float x1 = frf[s * 5120 + (icb + 2 * p + 1) * 160 + h];
            unsigned h0 = f2b(x0), h1 = f2b(x1);
            unsigned l0 = f2b(x0 - b2f(h0)), l1 = f2b(x1 - b2f(h1));
            hw_[p] = h0 | (h1 << 16);
            lw_[p] = l0 | (l1 << 16);
        }
        uint4 hv = {hw_[0], hw_[1], hw_[2], hw_[3]};
        uint4 lv = {lw_[0], lw_[1], lw_[2], lw_[3]};
        size_t o = (size_t)(b * 160 + w0 + s) * 5120 + word * 8;
        *(uint4*)(outb + o) = hv;
        *(uint4*)(outb + (size_t)PLANE + o) = lv;    // lo plane offset = PLANE u16s
    }
}

// ---------------- attention: MFMA bf16; q/k/t all read as frag images from global ----------------
__global__ __launch_bounds__(320) void k_att(float* __restrict__ ws) {
    __shared__ char Sb[51200];       // wave-private S slots: 50 x 64 lanes x 16B
    const int tid = threadIdx.x;
    const int bid = blockIdx.x;
    const int r8 = bid & 7, qq = bid >> 3;   // XCD swizzle
    const int b = qq / 20;
    const int w = r8 * 20 + (qq % 20);
    const int bw = b * Ww + w;
    const int wv = tid >> 6;
    const int l  = tid & 63;
    const int g  = l >> 4;
    const int c  = l & 15;
    const int slice = b * 160 + w;

    const u16* __restrict__ qh = (const u16*)(ws + OFF_V)   + (size_t)slice * 5120;
    const u16* __restrict__ ql = qh + (size_t)PLANE;
    const u16* __restrict__ kh = (const u16*)(ws + OFF_TPF) + (size_t)slice * 5120;
    const u16* __restrict__ kl = kh + (size_t)PLANE;

    bf16x8 bq[2][2];
#pragma unroll
    for (int ct = 0; ct < 2; ct++) {
        int tau = 2 * wv + ct;
        bq[ct][0] = *(const bf16x8*)(qh + (tau * 64 + l) * 8);
        bq[ct][1] = *(const bf16x8*)(ql + (tau * 64 + l) * 8);
    }
    f32x4 acc[10][2];
    f32x4 z4 = {0.f, 0.f, 0.f, 0.f};
#pragma unroll
    for (int rt = 0; rt < 10; rt++) { acc[rt][0] = z4; acc[rt][1] = z4; }
#pragma unroll
    for (int rt = 0; rt < 10; rt++) {
        bf16x8 ah = *(const bf16x8*)(kh + (rt * 64 + l) * 8);
        bf16x8 al = *(const bf16x8*)(kl + (rt * 64 + l) * 8);
#pragma unroll
        for (int ct = 0; ct < 2; ct++) {
            acc[rt][ct] = __builtin_amdgcn_mfma_f32_16x16x32_bf16(ah, bq[ct][0], acc[rt][ct], 0, 0, 0);
            acc[rt][ct] = __builtin_amdgcn_mfma_f32_16x16x32_bf16(ah, bq[ct][1], acc[rt][ct], 0, 0, 0);
            acc[rt][ct] = __builtin_amdgcn_mfma_f32_16x16x32_bf16(al, bq[ct][0], acc[rt][ct], 0, 0, 0);
        }
    }

    float mx[2] = {-3.4e38f, -3.4e38f};
#pragma unroll
    for (int rt = 0; rt < 10; rt++)
#pragma unroll
        for (int ct = 0; ct < 2; ct++)
#pragma unroll
            for (int j = 0; j < 4; j++) mx[ct] = fmaxf(mx[ct], acc[rt][ct][j]);
#pragma unroll
    for (int ct = 0; ct < 2; ct++) {
        mx[ct] = fmaxf(mx[ct], __shfl_xor(mx[ct], 16));
        mx[ct] = fmaxf(mx[ct], __shfl_xor(mx[ct], 32));
    }
    float sm[2] = {0.f, 0.f};
#pragma unroll
    for (int rt = 0; rt < 10; rt++)
#pragma unroll
        for (int ct = 0; ct < 2; ct++)
#pragma unroll
            for (int j = 0; j < 4; j++) {
                float e = __expf(acc[rt][ct][j] - mx[ct]);
                acc[rt][ct][j] = e;
                sm[ct] += e;
            }
#pragma unroll
    for (int ct = 0; ct < 2; ct++) {
        sm[ct] += __shfl_xor(sm[ct], 16);
        sm[ct] += __shfl_xor(sm[ct], 32);
    }
    float inv[2] = {1.f / sm[0], 1.f / sm[1]};

    // S repack: wave-private slots -> no barriers needed (lgkmcnt orders within wave)
#pragma unroll
    for (int rt = 0; rt < 10; rt++) {
#pragma unroll
        for (int ct = 0; ct < 2; ct++) {
            float p0 = acc[rt][ct][0] * inv[ct];
            float p1 = acc[rt][ct][1] * inv[ct];
            float p2 = acc[rt][ct][2] * inv[ct];
            float p3 = acc[rt][ct][3] * inv[ct];
            unsigned d0 = f2b(p0) | (f2b(p1) << 16);
            unsigned d1 = f2b(p2) | (f2b(p3) << 16);
            int Lf = c + 16 * (2 * (rt & 1) + (g >> 1));
            char* dst = Sb + (((wv * 2 + ct) * 5 + (rt >> 1)) * 64 + Lf) * 16 + 8 * (g & 1);
            uint2 dd; dd.x = d0; dd.y = d1;
            *(uint2*)dst = dd;
        }
    }

    const u16* tf = (const u16*)(ws + OFF_T);
    u16* catb = (u16*)(ws + OFF_CAT);
    for (int d = 0; d < 3; d++) {
        const u16* tfd = tf + ((size_t)d * (Bb * Ww) + bw) * 5120;
        f32x4 po[2][2];
        po[0][0] = z4; po[0][1] = z4; po[1][0] = z4; po[1][1] = z4;
#pragma unroll
        for (int ks = 0; ks < 5; ks++) {
            bf16x8 a0 = *(const bf16x8*)(tfd + ((0 * 5 + ks) * 64 + l) * 8);   // coalesced 16B/lane
            bf16x8 a1 = *(const bf16x8*)(tfd + ((1 * 5 + ks) * 64 + l) * 8);
            bf16x8 s0 = *(bf16x8*)(Sb + (((wv * 2 + 0) * 5 + ks) * 64 + l) * 16);
            bf16x8 s1 = *(bf16x8*)(Sb + (((wv * 2 + 1) * 5 + ks) * 64 + l) * 16);
            po[0][0] = __builtin_amdgcn_mfma_f32_16x16x32_bf16(a0, s0, po[0][0], 0, 0, 0);
            po[0][1] = __builtin_amdgcn_mfma_f32_16x16x32_bf16(a0, s1, po[0][1], 0, 0, 0);
            po[1][0] = __builtin_amdgcn_mfma_f32_16x16x32_bf16(a1, s0, po[1][0], 0, 0, 0);
            po[1][1] = __builtin_amdgcn_mfma_f32_16x16x32_bf16(a1, s1, po[1][1], 0, 0, 0);
        }
#pragma unroll
        for (int jt = 0; jt < 2; jt++)
#pragma unroll
            for (int ct = 0; ct < 2; ct++) {
                int h1 = 32 * wv + 16 * ct + c;
                size_t idx = (size_t)d * PLANE + (size_t)bw * 5120 + h1 * 32 + 16 * jt + 4 * g;
                f32x4 v = po[jt][ct];
                uint2 dd;
                dd.x = f2b(v[0]) | (f2b(v[1]) << 16);
                dd.y = f2b(v[2]) | (f2b(v[3]) << 16);
                *(uint2*)(catb + idx) = dd;
            }
    }
}

// ---------------- output 1x1 conv: bf16 MFMA GEMM M=256,K=96,N=204800 ----------------
__global__ __launch_bounds__(256) void k_out(const float* __restrict__ feat,
                                             const float* __restrict__ ws,
                                             float* __restrict__ out) {
    __shared__ u16 Bs[12288];   // 24 slots(ks,nt) x 64 lanes x 8 bf16
    const int tid = threadIdx.x;
    const int wv = tid >> 6, l = tid & 63;
    const int g = l >> 4, c15 = l & 15;
    const int n0 = blockIdx.x * 128;
    const int b = n0 / HWn, hw0 = n0 % HWn;
    const u16* __restrict__ CATb = (const u16*)(ws + OFF_CAT);
    const u16* __restrict__ OWB = (const u16*)(ws + P_OWB);

#pragma unroll
    for (int ss = 0; ss < 6; ss++) {
        int s = tid + ss * 256;
        int sl = s & 63, si = s >> 6;    // si = ks*8+nt, 0..23
        int p = (si & 7) * 16 + (sl & 15);
        int hw = hw0 + p;
        int h = hw / Ww, w2 = hw % Ww;
        int j = (si >> 3) * 32 + (sl >> 4) * 8;
        size_t flat = ((size_t)(b * Ww + w2) * Hh + h) * 96 + j;
        *(uint4*)(&Bs[(si * 64 + sl) * 8]) = *(const uint4*)(CATb + flat);
    }
    bf16x8 af[4][3];
#pragma unroll
    for (int mt = 0; mt < 4; mt++)
#pragma unroll
        for (int ks = 0; ks < 3; ks++)
            af[mt][ks] = *(const bf16x8*)(OWB + (wv * 64 + mt * 16 + c15) * 96 + ks * 32 + g * 8);
    __syncthreads();
    const float alpha = ws[P_OA];

    f32x4 z4 = {0.f, 0.f, 0.f, 0.f};
#pragma unroll
    for (int np = 0; np < 2; np++) {
        f32x4 acc[4][4];
#pragma unroll
        for (int mt = 0; mt < 4; mt++)
#pragma unroll
            for (int ntl = 0; ntl < 4; ntl++) acc[mt][ntl] = z4;
#pragma unroll
        for (int ks = 0; ks < 3; ks++) {
            bf16x8 bf_[4];
#pragma unroll
            for (int ntl = 0; ntl < 4; ntl++)
                bf_[ntl] = *(const bf16x8*)(&Bs[((ks * 8 + np * 4 + ntl) * 64 + l) * 8]);
#pragma unroll
            for (int mt = 0; mt < 4; mt++)
#pragma unroll
                for (int ntl = 0; ntl < 4; ntl++)
                    acc[mt][ntl] = __builtin_amdgcn_mfma_f32_16x16x32_bf16(af[mt][ks], bf_[ntl], acc[mt][ntl], 0, 0, 0);
        }
#pragma unroll
        for (int mt = 0; mt < 4; mt++)
#pragma unroll
            for (int ntl = 0; ntl < 4; ntl++) {
                int p = (np * 4 + ntl) * 16 + c15;
#pragma unroll
                for (int jr = 0; jr < 4; jr++) {
                    int cch = wv * 64 + mt * 16 + 4 * g + jr;
                    size_t base = ((size_t)b * Cc + cch) * HWn + hw0 + p;
                    float y = acc[mt][ntl][jr] + ws[P_OB + cch] + feat[base];
                    out[base] = y >= 0.f ? y : alpha * y;
                }
            }
    }
}

extern "C" void kernel_launch(void* const* d_in, const int* in_sizes, int n_in,
                              void* d_out, int out_size, void* d_ws, size_t ws_size,
                              hipStream_t stream) {
    InPtrs ip;
    for (int i = 0; i < 40; i++) ip.p[i] = (const float*)d_in[i];
    float* ws = (float*)d_ws;
    const float* feat = (const float*)d_in[0];
    float* out = (float*)d_out;

    k_prep<<<304, 256, 0, stream>>>(ip, ws);
    k_vpad<<<1280, 64, 0, stream>>>(ws);
    k_qkv<<<1600, 256, 0, stream>>>(feat, ws);
    k_dconv<<<dim3(80, 8, 3), 256, 0, stream>>>(ws);
    k_tfrag<<<dim3(40, 8, 3), 256, 0, stream>>>(ws);
    (void)hipFuncSetAttribute(reinterpret_cast<const void*>(k_qkfrag),
                              hipFuncAttributeMaxDynamicSharedMemorySize, 81920);
    k_qkfrag<<<dim3(40, 8, 2), 256, 81920, stream>>>(ws);
    k_att<<<1280, 320, 0, stream>>>(ws);
    k_out<<<1600, 256, 0, stream>>>(feat, ws, out);
}